// Round 11
// baseline (860.334 us; speedup 1.0000x reference)
//
#include <hip/hip_runtime.h>
#include <hip/hip_bf16.h>
#include <cstdint>
#include <cstddef>

#define N_TOKENS  4096
#define DIM       2048
#define N_EXPERTS 32
#define TOPK      4
#define INTER     1408
#define TWO_INTER 2816
#define CAP       1024
#define T_ASSIGN  (N_TOKENS*TOPK)
#define BK        32

typedef __attribute__((ext_vector_type(8))) short short8;
typedef __attribute__((ext_vector_type(4))) float f32x4;

__device__ __forceinline__ unsigned pack_bf16(float a, float b) {
  unsigned ua = __builtin_bit_cast(unsigned, a);
  unsigned ub = __builtin_bit_cast(unsigned, b);
  ua = (ua + 0x8000u) >> 16;
  ub = (ub + 0x8000u) & 0xFFFF0000u;
  return ua | ub;
}
__device__ __forceinline__ float bf2f(unsigned u16) {
  return __builtin_bit_cast(float, u16 << 16);
}

__device__ __forceinline__ void gl_lds16(const void* g, void* l) {
  __builtin_amdgcn_global_load_lds(
      (const __attribute__((address_space(1))) unsigned int*)g,
      (__attribute__((address_space(3))) unsigned int*)l, 16, 0, 0);
}

// ---------------- routing build (+ inverse map pos) ----------------
__global__ void k_build(const int* __restrict__ tmask, const float* __restrict__ w,
                        const int* __restrict__ idx, int* __restrict__ counts,
                        int* __restrict__ tok, float* __restrict__ pb,
                        int* __restrict__ pos) {
  int i = blockIdx.x * 256 + threadIdx.x;
  if (i >= T_ASSIGN) return;
  int t = i >> 2;
  int e = idx[i];
  if (e < 0 || e >= N_EXPERTS) return;
  if (tmask[t] == 0) return;
  int r = atomicAdd(&counts[e], 1);
  if (r < CAP) {
    tok[e * CAP + r] = t;
    pb[e * CAP + r] = w[i];
    pos[i] = e * CAP + r;
  }
}

// ---------------- fp32 -> bf16 linear convert (x only) ----------------
__global__ __launch_bounds__(256) void k_conv(const float* __restrict__ src,
                                              __hip_bfloat16* __restrict__ dst, int n4) {
  int i = blockIdx.x * 256 + threadIdx.x;
  int stride = gridDim.x * 256;
  for (; i < n4; i += stride) {
    float4 v = *(const float4*)(src + (size_t)i * 4);
    *(uint2*)(dst + (size_t)i * 4) = make_uint2(pack_bf16(v.x, v.y), pack_bf16(v.z, v.w));
  }
}

// ---------------- combine: out[t] = sum_k y_bf16[pos[t][k]] ----------------
__global__ __launch_bounds__(256) void k_combine(const __hip_bfloat16* __restrict__ y,
                                                 const int* __restrict__ pos,
                                                 float* __restrict__ out) {
  int gid = blockIdx.x * 256 + threadIdx.x;
  int t  = gid >> 8;
  int c8 = (gid & 255) * 8;
  int4 p = *(const int4*)(pos + t * 4);
  float s[8] = {0.f, 0.f, 0.f, 0.f, 0.f, 0.f, 0.f, 0.f};
  #pragma unroll
  for (int k = 0; k < 4; ++k) {
    int pp = (k == 0) ? p.x : (k == 1) ? p.y : (k == 2) ? p.z : p.w;
    if (pp >= 0) {
      uint4 v = *(const uint4*)(y + (size_t)pp * DIM + c8);
      s[0] += bf2f(v.x & 0xffffu); s[1] += bf2f(v.x >> 16);
      s[2] += bf2f(v.y & 0xffffu); s[3] += bf2f(v.y >> 16);
      s[4] += bf2f(v.z & 0xffffu); s[5] += bf2f(v.z >> 16);
      s[6] += bf2f(v.w & 0xffffu); s[7] += bf2f(v.w >> 16);
    }
  }
  float* o = out + (size_t)t * DIM + c8;
  *(float4*)o       = make_float4(s[0], s[1], s[2], s[3]);
  *(float4*)(o + 4) = make_float4(s[4], s[5], s[6], s[7]);
}

// ====== persistent M256 x N128 x BK32 grouped GEMMs, fp32-direct B ======
// LDS per buffer (dbuf stride 32768):
//   A: [256 rows][64B bf16] 16KB — chunk swizzle phys = logical ^ ((row>>1)&3),
//      pre-applied on global source (gl_lds dest linear), XOR'd on ds_read (rch).
//   B: [32 k][128 n] fp32 16KB — k-XOR chunk swizzle: LDS 16B-chunk c_phys holds
//      global chunk c_log = c_phys ^ (((k>>3)&3)<<1). Stage applies inverse on the
//      GLOBAL column; reads XOR the same -> 2 lanes/bank (free, m136).
// B-frag: 8x ds_read_b32 (2-way) + 4x v_cvt_pk_bf16_f32 -> short8.
// Depth-1 pipeline, counted vmcnt(4). Per-XCD dynamic atomic work queue.

#define STG(tt, KT) do {                                                     \
    if ((tt) < (KT)) {                                                       \
      char* base_ = smem + ((tt) & 1) * 32768;                               \
      const int ka_ = (tt) * BK;                                             \
      gl_lds16(aR0 + ka_, base_ + w * 2048 + lane * 16);                     \
      gl_lds16(aR1 + ka_, base_ + w * 2048 + 1024 + lane * 16);              \
      const size_t kb_ = (size_t)(tt) * BK * LDB;                            \
      gl_lds16(bR0 + kb_, base_ + 16384 + tid * 16);                         \
      gl_lds16(bR1 + kb_, base_ + 16384 + 8192 + tid * 16);                  \
    }                                                                        \
  } while (0)

#define KLOOP(KT) do {                                                       \
    STG(0, KT);                                                              \
    _Pragma("unroll 1")                                                      \
    for (int t = 0; t < (KT); ++t) {                                         \
      STG(t + 1, KT);                                                        \
      if (t + 1 < (KT)) { asm volatile("s_waitcnt vmcnt(4)" ::: "memory"); } \
      else             { asm volatile("s_waitcnt vmcnt(0)" ::: "memory"); }  \
      __builtin_amdgcn_s_barrier();                                          \
      const char* Ab_ = smem + (t & 1) * 32768;                              \
      const float* Bf_ = (const float*)(Ab_ + 16384) + kb8 * 128 + li;       \
      short8 af_[4];                                                         \
      _Pragma("unroll")                                                      \
      for (int mi_ = 0; mi_ < 4; ++mi_)                                      \
        af_[mi_] = *(const short8*)(Ab_ + (wr * 64 + mi_ * 16 + (lane & 15)) * 64 + rch); \
      _Pragma("unroll")                                                      \
      for (int ni_ = 0; ni_ < 4; ++ni_) {                                    \
        const int cp_ = (cb + ni_ * 4) ^ cx;                                 \
        const float* q_ = Bf_ + cp_ * 4;                                     \
        float f0_ = q_[0],   f1_ = q_[128], f2_ = q_[256], f3_ = q_[384];    \
        float f4_ = q_[512], f5_ = q_[640], f6_ = q_[768], f7_ = q_[896];    \
        unsigned w0_, w1_, w2_, w3_;                                         \
        asm("v_cvt_pk_bf16_f32 %0, %1, %2" : "=v"(w0_) : "v"(f0_), "v"(f1_)); \
        asm("v_cvt_pk_bf16_f32 %0, %1, %2" : "=v"(w1_) : "v"(f2_), "v"(f3_)); \
        asm("v_cvt_pk_bf16_f32 %0, %1, %2" : "=v"(w2_) : "v"(f4_), "v"(f5_)); \
        asm("v_cvt_pk_bf16_f32 %0, %1, %2" : "=v"(w3_) : "v"(f6_), "v"(f7_)); \
        uint4 uu_ = make_uint4(w0_, w1_, w2_, w3_);                          \
        short8 bf_ = __builtin_bit_cast(short8, uu_);                        \
        __builtin_amdgcn_s_setprio(1);                                       \
        _Pragma("unroll")                                                    \
        for (int mi_ = 0; mi_ < 4; ++mi_)                                    \
          acc[mi_][ni_] = __builtin_amdgcn_mfma_f32_16x16x32_bf16(           \
              af_[mi_], bf_, acc[mi_][ni_], 0, 0, 0);                        \
        __builtin_amdgcn_s_setprio(0);                                       \
      }                                                                      \
      __builtin_amdgcn_s_barrier();                                          \
    }                                                                        \
  } while (0)

// GEMM1: act = GEGLU( gather(xb) @ gup[e] ) * prob   (gup fp32 native [d][n])
__global__ __launch_bounds__(512, 4) void k_gemm1p(
    const __hip_bfloat16* __restrict__ xb, const float* __restrict__ gup,
    const int* __restrict__ counts, const int* __restrict__ tok,
    const float* __restrict__ pb, __hip_bfloat16* __restrict__ act,
    int* __restrict__ qh)
{
  __shared__ char smem[65536];
  __shared__ int s_item;
  const int NT = TWO_INTER / 128;   // 22
  const int KT = DIM / BK;          // 64
  const size_t LDB = TWO_INTER;
  const int xcd = blockIdx.x & 7;
  const int tid = threadIdx.x, lane = tid & 63, w = tid >> 6;  // 8 waves
  const int wr = w >> 1, wc = w & 1;                            // 4M x 2N
  const int csw = ((lane & 3) ^ ((lane >> 3) & 3)) * 8;         // A src col swizzle
  const int rch = (((lane >> 4) ^ ((lane >> 1) & 3)) << 4);     // A read chunk
  const int rA0 = w * 32 + (lane >> 2);                         // A staging row
  const int bk0 = tid >> 5;                                     // B staging k (0..15)
  const int bc0 = (tid & 31) ^ (((tid >> 8) & 1) << 1);         // B src chunk, k-XOR
  const int bc1 = bc0 ^ 4;                                      // for k+16 rows
  const int cb  = wc * 16 + ((lane & 15) >> 2);                 // B read chunk base
  const int cx  = (lane >> 4) << 1;                             // B read k-XOR
  const int kb8 = (lane >> 4) << 3;                             // B read k base
  const int li  = lane & 3;                                     // float within chunk

  int mtcs[4], pre[5];
  pre[0] = 0;
  #pragma unroll
  for (int ei = 0; ei < 4; ++ei) {
    int cc = counts[xcd * 4 + ei]; cc = cc > CAP ? CAP : cc;
    mtcs[ei] = (cc + 255) >> 8;
    pre[ei + 1] = pre[ei] + NT * mtcs[ei];
  }
  const int total = pre[4];

  for (;;) {
    if (tid == 0) s_item = atomicAdd(&qh[xcd], 1);
    __syncthreads();
    const int it = s_item;
    if (it >= total) break;
    int ei = (it >= pre[1]) + (it >= pre[2]) + (it >= pre[3]);
    int loc = it - pre[ei];
    int mtc = mtcs[ei];
    int nt = loc / mtc, mt = loc - nt * mtc;
    const int e = xcd * 4 + ei;
    const int m0 = mt * 256, n0 = nt * 128;

    const float* gW = gup + (size_t)e * DIM * TWO_INTER + n0;
    const __hip_bfloat16* aR0 = xb + (size_t)tok[e * CAP + m0 + rA0] * DIM + csw;
    const __hip_bfloat16* aR1 = xb + (size_t)tok[e * CAP + m0 + rA0 + 16] * DIM + csw;
    const float* bR0 = gW + (size_t)bk0 * LDB + bc0 * 4;
    const float* bR1 = gW + (size_t)(bk0 + 16) * LDB + bc1 * 4;

    f32x4 acc[4][4];
    #pragma unroll
    for (int i = 0; i < 4; ++i)
      #pragma unroll
      for (int j = 0; j < 4; ++j) acc[i][j] = (f32x4){0.f, 0.f, 0.f, 0.f};

    KLOOP(KT);

    // epilogue: GEGLU * prob -> bf16 act
    const int colp = lane & 15;
    const int rgrp = lane >> 4;
    #pragma unroll
    for (int mi = 0; mi < 4; ++mi) {
      #pragma unroll
      for (int j = 0; j < 4; ++j) {
        int rowl = wr * 64 + mi * 16 + rgrp * 4 + j;
        float prob = pb[e * CAP + m0 + rowl];
        size_t arow = (size_t)(e * CAP + m0 + rowl) * INTER;
        #pragma unroll
        for (int ni = 0; ni < 4; ++ni) {
          float v = acc[mi][ni][j];
          float other = __shfl_xor(v, 1, 64);
          if ((lane & 1) == 0) {
            float gate = fminf(v, 7.0f);
            float up   = fminf(fmaxf(other, -7.0f), 7.0f);
            float glu  = gate / (1.0f + __expf(-1.702f * gate));
            float a    = glu * (up + 1.0f) * prob;
            int nh = n0 + wc * 64 + ni * 16 + colp;
            act[arow + (nh >> 1)] = __float2bfloat16(a);
          }
        }
      }
    }
    __syncthreads();
  }
}

// GEMM2: y_bf16 = act @ down[e]   (down fp32 native [k][n]); plain stores
__global__ __launch_bounds__(512, 4) void k_gemm2p(
    const __hip_bfloat16* __restrict__ act, const float* __restrict__ down,
    const int* __restrict__ counts, __hip_bfloat16* __restrict__ y,
    int* __restrict__ qh)
{
  __shared__ char smem[65536];
  __shared__ int s_item;
  const int NT = DIM / 128;     // 16
  const int KT = INTER / BK;    // 44
  const size_t LDB = DIM;
  const int xcd = blockIdx.x & 7;
  const int tid = threadIdx.x, lane = tid & 63, w = tid >> 6;
  const int wr = w >> 1, wc = w & 1;
  const int csw = ((lane & 3) ^ ((lane >> 3) & 3)) * 8;
  const int rch = (((lane >> 4) ^ ((lane >> 1) & 3)) << 4);
  const int rA0 = w * 32 + (lane >> 2);
  const int bk0 = tid >> 5;
  const int bc0 = (tid & 31) ^ (((tid >> 8) & 1) << 1);
  const int bc1 = bc0 ^ 4;
  const int cb  = wc * 16 + ((lane & 15) >> 2);
  const int cx  = (lane >> 4) << 1;
  const int kb8 = (lane >> 4) << 3;
  const int li  = lane & 3;

  int mtcs[4], pre[5];
  pre[0] = 0;
  #pragma unroll
  for (int ei = 0; ei < 4; ++ei) {
    int cc = counts[xcd * 4 + ei]; cc = cc > CAP ? CAP : cc;
    mtcs[ei] = (cc + 255) >> 8;
    pre[ei + 1] = pre[ei] + NT * mtcs[ei];
  }
  const int total = pre[4];

  for (;;) {
    if (tid == 0) s_item = atomicAdd(&qh[xcd], 1);
    __syncthreads();
    const int it = s_item;
    if (it >= total) break;
    int ei = (it >= pre[1]) + (it >= pre[2]) + (it >= pre[3]);
    int loc = it - pre[ei];
    int mtc = mtcs[ei];
    int nt = loc / mtc, mt = loc - nt * mtc;
    const int e = xcd * 4 + ei;
    const int m0 = mt * 256, n0 = nt * 128;

    const float* dW = down + (size_t)e * INTER * DIM + n0;
    const __hip_bfloat16* aR0 = act + (size_t)(e * CAP + m0 + rA0) * INTER + csw;
    const __hip_bfloat16* aR1 = act + (size_t)(e * CAP + m0 + rA0 + 16) * INTER + csw;
    const float* bR0 = dW + (size_t)bk0 * LDB + bc0 * 4;
    const float* bR1 = dW + (size_t)(bk0 + 16) * LDB + bc1 * 4;

    f32x4 acc[4][4];
    #pragma unroll
    for (int i = 0; i < 4; ++i)
      #pragma unroll
      for (int j = 0; j < 4; ++j) acc[i][j] = (f32x4){0.f, 0.f, 0.f, 0.f};

    KLOOP(KT);

    const int colp = lane & 15;
    const int rgrp = lane >> 4;
    #pragma unroll
    for (int mi = 0; mi < 4; ++mi) {
      #pragma unroll
      for (int j = 0; j < 4; ++j) {
        int rowl = wr * 64 + mi * 16 + rgrp * 4 + j;
        __hip_bfloat16* yrow = y + (size_t)(e * CAP + m0 + rowl) * DIM + n0;
        #pragma unroll
        for (int ni = 0; ni < 4; ++ni)
          yrow[wc * 64 + ni * 16 + colp] = __float2bfloat16(acc[mi][ni][j]);
      }
    }
    __syncthreads();
  }
}

// ================= launch =================

extern "C" void kernel_launch(void* const* d_in, const int* in_sizes, int n_in,
                              void* d_out, int out_size, void* d_ws, size_t ws_size,
                              hipStream_t stream) {
  const float* x     = (const float*)d_in[0];
  const int*   tmask = (const int*)d_in[1];
  const float* w     = (const float*)d_in[2];
  const int*   idx   = (const int*)d_in[3];
  const float* gup   = (const float*)d_in[4];
  const float* down  = (const float*)d_in[5];
  float* out = (float*)d_out;

  char* ws = (char*)d_ws;
  const size_t off_qh1   = 128;
  const size_t off_qh2   = 160;
  const size_t off_tok   = 256;
  const size_t off_pb    = off_tok + 131072;
  const size_t off_pos   = off_pb + 131072;
  const size_t off_act   = off_pos + 65536;
  const size_t act_bytes = (size_t)N_EXPERTS * CAP * INTER * 2;
  const size_t off_xb    = off_act + act_bytes;
  const size_t xb_bytes  = (size_t)N_TOKENS * DIM * 2;
  const size_t off_y     = off_xb + xb_bytes;

  int*   counts = (int*)ws;
  int*   qh1    = (int*)(ws + off_qh1);
  int*   qh2    = (int*)(ws + off_qh2);
  int*   tok    = (int*)(ws + off_tok);
  float* pbuf   = (float*)(ws + off_pb);
  int*   pos    = (int*)(ws + off_pos);
  __hip_bfloat16* act = (__hip_bfloat16*)(ws + off_act);
  __hip_bfloat16* xb  = (__hip_bfloat16*)(ws + off_xb);
  __hip_bfloat16* y   = (__hip_bfloat16*)(ws + off_y);

  hipMemsetAsync(ws, 0, off_pos, stream);
  hipMemsetAsync(ws + off_pos, 0xFF, 65536, stream);
  k_build<<<(T_ASSIGN + 255) / 256, 256, 0, stream>>>(tmask, w, idx, counts, tok, pbuf, pos);

  k_conv<<<2048, 256, 0, stream>>>(x, xb, (N_TOKENS * DIM) / 4);

  k_gemm1p<<<512, 512, 0, stream>>>(xb, gup, counts, tok, pbuf, act, qh1);
  k_gemm2p<<<512, 512, 0, stream>>>(act, down, counts, y, qh2);
  k_combine<<<N_TOKENS, 256, 0, stream>>>(y, pos, out);
}

// Round 13
// 705.150 us; speedup vs baseline: 1.2201x; 1.2201x over previous
//
#include <hip/hip_runtime.h>
#include <hip/hip_bf16.h>
#include <cstdint>
#include <cstddef>

#define N_TOKENS  4096
#define DIM       2048
#define N_EXPERTS 32
#define TOPK      4
#define INTER     1408
#define TWO_INTER 2816
#define CAP       1024
#define T_ASSIGN  (N_TOKENS*TOPK)
#define BK        32

typedef __attribute__((ext_vector_type(8))) short short8;
typedef __attribute__((ext_vector_type(4))) float f32x4;

__device__ __forceinline__ unsigned pack_bf16(float a, float b) {
  unsigned ua = __builtin_bit_cast(unsigned, a);
  unsigned ub = __builtin_bit_cast(unsigned, b);
  ua = (ua + 0x8000u) >> 16;
  ub = (ub + 0x8000u) & 0xFFFF0000u;
  return ua | ub;
}
__device__ __forceinline__ float bf2f(unsigned u16) {
  return __builtin_bit_cast(float, u16 << 16);
}

__device__ __forceinline__ void gl_lds16(const void* g, void* l) {
  __builtin_amdgcn_global_load_lds(
      (const __attribute__((address_space(1))) unsigned int*)g,
      (__attribute__((address_space(3))) unsigned int*)l, 16, 0, 0);
}

// ---------------- routing build (+ inverse map pos) ----------------
__global__ void k_build(const int* __restrict__ tmask, const float* __restrict__ w,
                        const int* __restrict__ idx, int* __restrict__ counts,
                        int* __restrict__ tok, float* __restrict__ pb,
                        int* __restrict__ pos) {
  int i = blockIdx.x * 256 + threadIdx.x;
  if (i >= T_ASSIGN) return;
  int t = i >> 2;
  int e = idx[i];
  if (e < 0 || e >= N_EXPERTS) return;
  if (tmask[t] == 0) return;
  int r = atomicAdd(&counts[e], 1);
  if (r < CAP) {
    tok[e * CAP + r] = t;
    pb[e * CAP + r] = w[i];
    pos[i] = e * CAP + r;
  }
}

// ---------------- fp32 -> bf16 linear convert (x only) ----------------
__global__ __launch_bounds__(256) void k_conv(const float* __restrict__ src,
                                              __hip_bfloat16* __restrict__ dst, int n4) {
  int i = blockIdx.x * 256 + threadIdx.x;
  int stride = gridDim.x * 256;
  for (; i < n4; i += stride) {
    float4 v = *(const float4*)(src + (size_t)i * 4);
    *(uint2*)(dst + (size_t)i * 4) = make_uint2(pack_bf16(v.x, v.y), pack_bf16(v.z, v.w));
  }
}

// ---------------- combine: out[t] = sum_k y_bf16[pos[t][k]] ----------------
__global__ __launch_bounds__(256) void k_combine(const __hip_bfloat16* __restrict__ y,
                                                 const int* __restrict__ pos,
                                                 float* __restrict__ out) {
  int gid = blockIdx.x * 256 + threadIdx.x;
  int t  = gid >> 8;
  int c8 = (gid & 255) * 8;
  int4 p = *(const int4*)(pos + t * 4);
  float s[8] = {0.f, 0.f, 0.f, 0.f, 0.f, 0.f, 0.f, 0.f};
  #pragma unroll
  for (int k = 0; k < 4; ++k) {
    int pp = (k == 0) ? p.x : (k == 1) ? p.y : (k == 2) ? p.z : p.w;
    if (pp >= 0) {
      uint4 v = *(const uint4*)(y + (size_t)pp * DIM + c8);
      s[0] += bf2f(v.x & 0xffffu); s[1] += bf2f(v.x >> 16);
      s[2] += bf2f(v.y & 0xffffu); s[3] += bf2f(v.y >> 16);
      s[4] += bf2f(v.z & 0xffffu); s[5] += bf2f(v.z >> 16);
      s[6] += bf2f(v.w & 0xffffu); s[7] += bf2f(v.w >> 16);
    }
  }
  float* o = out + (size_t)t * DIM + c8;
  *(float4*)o       = make_float4(s[0], s[1], s[2], s[3]);
  *(float4*)(o + 4) = make_float4(s[4], s[5], s[6], s[7]);
}

// ====== persistent M256 x N128 x BK32 grouped GEMMs, reg-staged bf16 B ======
// LDS 48KB: A dbuf 2x16KB [0,32K): [256 rows][64B], chunk swz phys=log^((row>>1)&3),
//   staged via gl_lds (pre-swizzled global col, distance-1 -> always opposite buffer).
// Bbf dbuf 2x8KB [32K,48K): bf16 [128 n][64B = 32 k], same swizzle family.
// B path: 8 fully-coalesced global_load_dword (bn=tid&127) at distance 2 -> regs ->
//   pack_bf16 -> one ds_write_b128 (banks: each 8-lane group covers all 32).
// Sync per tile: issue A(t+1); vmcnt(10) [=B(t+1)8+A(t+1)2 in flight]; ds_write B(t);
//   load B(t+2) regs; lgkmcnt(0); barrier; pure-b128 frag reads + 32 MFMA; barrier.

#define TILE_STEP(t, bcur, KT, LDB) do {                                    \
    if ((t) + 1 < (KT)) {                                                   \
      char* ad_ = smem + (((t) + 1) & 1) * 16384 + w * 2048 + lane * 16;    \
      gl_lds16(aP0 + (size_t)((t) + 1) * BK, ad_);                          \
      gl_lds16(aP1 + (size_t)((t) + 1) * BK, ad_ + 1024);                   \
      asm volatile("s_waitcnt vmcnt(10)" ::: "memory");                     \
    } else {                                                                \
      asm volatile("s_waitcnt vmcnt(0)" ::: "memory");                      \
    }                                                                       \
    { uint4 u_;                                                             \
      u_.x = pack_bf16(bcur[0], bcur[1]);                                   \
      u_.y = pack_bf16(bcur[2], bcur[3]);                                   \
      u_.z = pack_bf16(bcur[4], bcur[5]);                                   \
      u_.w = pack_bf16(bcur[6], bcur[7]);                                   \
      *(uint4*)(bbf + ((t) & 1) * 8192 + bwoff) = u_; }                     \
    if ((t) + 2 < (KT)) {                                                   \
      const float* p_ = bG + (size_t)((t) + 2) * BK * (LDB);                \
      _Pragma("unroll")                                                     \
      for (int j_ = 0; j_ < 8; ++j_) bcur[j_] = p_[(size_t)j_ * (LDB)];     \
    }                                                                       \
    asm volatile("s_waitcnt lgkmcnt(0)" ::: "memory");                      \
    __builtin_amdgcn_s_barrier();                                           \
    __builtin_amdgcn_sched_barrier(0);                                      \
    { const char* Ab_ = smem + ((t) & 1) * 16384;                           \
      const char* Bb_ = bbf + ((t) & 1) * 8192;                             \
      short8 af_[4], bf_[4];                                                \
      _Pragma("unroll")                                                     \
      for (int mi_ = 0; mi_ < 4; ++mi_)                                     \
        af_[mi_] = *(const short8*)(Ab_ + (wr * 64 + mi_ * 16 + (lane & 15)) * 64 + rch); \
      _Pragma("unroll")                                                     \
      for (int ni_ = 0; ni_ < 4; ++ni_)                                     \
        bf_[ni_] = *(const short8*)(Bb_ + (wc * 64 + ni_ * 16 + (lane & 15)) * 64 + rch); \
      __builtin_amdgcn_s_setprio(1);                                        \
      _Pragma("unroll")                                                     \
      for (int mi_ = 0; mi_ < 4; ++mi_)                                     \
        _Pragma("unroll")                                                   \
        for (int ni_ = 0; ni_ < 4; ++ni_)                                   \
          acc[mi_][ni_] = __builtin_amdgcn_mfma_f32_16x16x32_bf16(          \
              af_[mi_], bf_[ni_], acc[mi_][ni_], 0, 0, 0);                  \
      __builtin_amdgcn_s_setprio(0); }                                      \
    __builtin_amdgcn_s_barrier();                                           \
  } while (0)

#define GKLOOP(KT, LDB) do {                                                \
    {                                                                       \
      char* ad0_ = smem + w * 2048 + lane * 16;                             \
      gl_lds16(aP0, ad0_);                                                  \
      gl_lds16(aP1, ad0_ + 1024);                                           \
      _Pragma("unroll")                                                     \
      for (int j_ = 0; j_ < 8; ++j_) bE[j_] = bG[(size_t)j_ * (LDB)];       \
      const float* p1_ = bG + (size_t)BK * (LDB);                           \
      _Pragma("unroll")                                                     \
      for (int j_ = 0; j_ < 8; ++j_) bO[j_] = p1_[(size_t)j_ * (LDB)];      \
    }                                                                       \
    _Pragma("unroll 1")                                                     \
    for (int t = 0; t < (KT); t += 2) {                                     \
      TILE_STEP(t,     bE, (KT), (LDB));                                    \
      TILE_STEP(t + 1, bO, (KT), (LDB));                                    \
    }                                                                       \
  } while (0)

// GEMM1: act = GEGLU( gather(xb) @ gup[e] ) * prob   (gup fp32 native [k][n])
__global__ __launch_bounds__(512, 4) void k_gemm1p(
    const __hip_bfloat16* __restrict__ xb, const float* __restrict__ gup,
    const int* __restrict__ counts, const int* __restrict__ tok,
    const float* __restrict__ pb, __hip_bfloat16* __restrict__ act,
    int* __restrict__ qh)
{
  __shared__ char smem[49152];
  __shared__ int s_item;
  char* bbf = smem + 32768;
  const int NT = TWO_INTER / 128;   // 22
  const int KT = DIM / BK;          // 64
  const int xcd = blockIdx.x & 7;
  const int tid = threadIdx.x, lane = tid & 63, w = tid >> 6;  // 8 waves
  const int wr = w >> 1, wc = w & 1;                            // 4M x 2N
  const int csw = ((lane & 3) ^ ((lane >> 3) & 3)) * 8;         // A src col swizzle
  const int rch = (((lane >> 4) ^ ((lane >> 1) & 3)) << 4);     // frag read chunk swz
  const int rA0 = w * 32 + (lane >> 2);                         // A staging row
  const int bn  = tid & 127;                                    // B column n
  const int bkc = tid >> 7;                                     // B k-chunk (8 k each)
  const int bwoff = bn * 64 + ((bkc ^ ((bn >> 1) & 3)) << 4);   // swizzled write off

  int mtcs[4], pre[5];
  pre[0] = 0;
  #pragma unroll
  for (int ei = 0; ei < 4; ++ei) {
    int cc = counts[xcd * 4 + ei]; cc = cc > CAP ? CAP : cc;
    mtcs[ei] = (cc + 255) >> 8;
    pre[ei + 1] = pre[ei] + NT * mtcs[ei];
  }
  const int total = pre[4];

  for (;;) {
    if (tid == 0) s_item = atomicAdd(&qh[xcd], 1);
    __syncthreads();
    const int it = s_item;
    if (it >= total) break;
    int ei = (it >= pre[1]) + (it >= pre[2]) + (it >= pre[3]);
    int loc = it - pre[ei];
    int mtc = mtcs[ei];
    int nt = loc / mtc, mt = loc - nt * mtc;
    const int e = xcd * 4 + ei;
    const int m0 = mt * 256, n0 = nt * 128;

    const float* gW = gup + (size_t)e * DIM * TWO_INTER;
    const __hip_bfloat16* aP0 = xb + (size_t)tok[e * CAP + m0 + rA0] * DIM + csw;
    const __hip_bfloat16* aP1 = xb + (size_t)tok[e * CAP + m0 + rA0 + 16] * DIM + csw;
    const float* bG = gW + (size_t)(bkc * 8) * TWO_INTER + n0 + bn;

    f32x4 acc[4][4];
    #pragma unroll
    for (int i = 0; i < 4; ++i)
      #pragma unroll
      for (int j = 0; j < 4; ++j) acc[i][j] = (f32x4){0.f, 0.f, 0.f, 0.f};
    float bE[8], bO[8];

    GKLOOP(KT, TWO_INTER);

    // epilogue: GEGLU * prob -> bf16 act
    const int colp = lane & 15;
    const int rgrp = lane >> 4;
    #pragma unroll
    for (int mi = 0; mi < 4; ++mi) {
      #pragma unroll
      for (int j = 0; j < 4; ++j) {
        int rowl = wr * 64 + mi * 16 + rgrp * 4 + j;
        float prob = pb[e * CAP + m0 + rowl];
        size_t arow = (size_t)(e * CAP + m0 + rowl) * INTER;
        #pragma unroll
        for (int ni = 0; ni < 4; ++ni) {
          float v = acc[mi][ni][j];
          float other = __shfl_xor(v, 1, 64);
          if ((lane & 1) == 0) {
            float gate = fminf(v, 7.0f);
            float up   = fminf(fmaxf(other, -7.0f), 7.0f);
            float glu  = gate / (1.0f + __expf(-1.702f * gate));
            float a    = glu * (up + 1.0f) * prob;
            int nh = n0 + wc * 64 + ni * 16 + colp;
            act[arow + (nh >> 1)] = __float2bfloat16(a);
          }
        }
      }
    }
    __syncthreads();
  }
}

// GEMM2: y_bf16 = act @ down[e]   (down fp32 native [k][n]); plain stores
__global__ __launch_bounds__(512, 4) void k_gemm2p(
    const __hip_bfloat16* __restrict__ act, const float* __restrict__ down,
    const int* __restrict__ counts, __hip_bfloat16* __restrict__ y,
    int* __restrict__ qh)
{
  __shared__ char smem[49152];
  __shared__ int s_item;
  char* bbf = smem + 32768;
  const int NT = DIM / 128;     // 16
  const int KT = INTER / BK;    // 44
  const int xcd = blockIdx.x & 7;
  const int tid = threadIdx.x, lane = tid & 63, w = tid >> 6;
  const int wr = w >> 1, wc = w & 1;
  const int csw = ((lane & 3) ^ ((lane >> 3) & 3)) * 8;
  const int rch = (((lane >> 4) ^ ((lane >> 1) & 3)) << 4);
  const int rA0 = w * 32 + (lane >> 2);
  const int bn  = tid & 127;
  const int bkc = tid >> 7;
  const int bwoff = bn * 64 + ((bkc ^ ((bn >> 1) & 3)) << 4);

  int mtcs[4], pre[5];
  pre[0] = 0;
  #pragma unroll
  for (int ei = 0; ei < 4; ++ei) {
    int cc = counts[xcd * 4 + ei]; cc = cc > CAP ? CAP : cc;
    mtcs[ei] = (cc + 255) >> 8;
    pre[ei + 1] = pre[ei] + NT * mtcs[ei];
  }
  const int total = pre[4];

  for (;;) {
    if (tid == 0) s_item = atomicAdd(&qh[xcd], 1);
    __syncthreads();
    const int it = s_item;
    if (it >= total) break;
    int ei = (it >= pre[1]) + (it >= pre[2]) + (it >= pre[3]);
    int loc = it - pre[ei];
    int mtc = mtcs[ei];
    int nt = loc / mtc, mt = loc - nt * mtc;
    const int e = xcd * 4 + ei;
    const int m0 = mt * 256, n0 = nt * 128;

    const float* dW = down + (size_t)e * INTER * DIM;
    const __hip_bfloat16* aP0 = act + (size_t)(e * CAP + m0 + rA0) * INTER + csw;
    const __hip_bfloat16* aP1 = act + (size_t)(e * CAP + m0 + rA0 + 16) * INTER + csw;
    const float* bG = dW + (size_t)(bkc * 8) * DIM + n0 + bn;

    f32x4 acc[4][4];
    #pragma unroll
    for (int i = 0; i < 4; ++i)
      #pragma unroll
      for (int j = 0; j < 4; ++j) acc[i][j] = (f32x4){0.f, 0.f, 0.f, 0.f};
    float bE[8], bO[8];

    GKLOOP(KT, DIM);

    const int colp = lane & 15;
    const int rgrp = lane >> 4;
    #pragma unroll
    for (int mi = 0; mi < 4; ++mi) {
      #pragma unroll
      for (int j = 0; j < 4; ++j) {
        int rowl = wr * 64 + mi * 16 + rgrp * 4 + j;
        __hip_bfloat16* yrow = y + (size_t)(e * CAP + m0 + rowl) * DIM + n0;
        #pragma unroll
        for (int ni = 0; ni < 4; ++ni)
          yrow[wc * 64 + ni * 16 + colp] = __float2bfloat16(acc[mi][ni][j]);
      }
    }
    __syncthreads();
  }
}

// ================= launch =================

extern "C" void kernel_launch(void* const* d_in, const int* in_sizes, int n_in,
                              void* d_out, int out_size, void* d_ws, size_t ws_size,
                              hipStream_t stream) {
  const float* x     = (const float*)d_in[0];
  const int*   tmask = (const int*)d_in[1];
  const float* w     = (const float*)d_in[2];
  const int*   idx   = (const int*)d_in[3];
  const float* gup   = (const float*)d_in[4];
  const float* down  = (const float*)d_in[5];
  float* out = (float*)d_out;

  char* ws = (char*)d_ws;
  const size_t off_qh1   = 128;
  const size_t off_qh2   = 160;
  const size_t off_tok   = 256;
  const size_t off_pb    = off_tok + 131072;
  const size_t off_pos   = off_pb + 131072;
  const size_t off_act   = off_pos + 65536;
  const size_t act_bytes = (size_t)N_EXPERTS * CAP * INTER * 2;
  const size_t off_xb    = off_act + act_bytes;
  const size_t xb_bytes  = (size_t)N_TOKENS * DIM * 2;
  const size_t off_y     = off_xb + xb_bytes;

  int*   counts = (int*)ws;
  int*   qh1    = (int*)(ws + off_qh1);
  int*   qh2    = (int*)(ws + off_qh2);
  int*   tok    = (int*)(ws + off_tok);
  float* pbuf   = (float*)(ws + off_pb);
  int*   pos    = (int*)(ws + off_pos);
  __hip_bfloat16* act = (__hip_bfloat16*)(ws + off_act);
  __hip_bfloat16* xb  = (__hip_bfloat16*)(ws + off_xb);
  __hip_bfloat16* y   = (__hip_bfloat16*)(ws + off_y);

  hipMemsetAsync(ws, 0, off_pos, stream);
  hipMemsetAsync(ws + off_pos, 0xFF, 65536, stream);
  k_build<<<(T_ASSIGN + 255) / 256, 256, 0, stream>>>(tmask, w, idx, counts, tok, pbuf, pos);

  k_conv<<<2048, 256, 0, stream>>>(x, xb, (N_TOKENS * DIM) / 4);

  k_gemm1p<<<512, 512, 0, stream>>>(xb, gup, counts, tok, pbuf, act, qh1);
  k_gemm2p<<<512, 512, 0, stream>>>(act, down, counts, y, qh2);
  k_combine<<<N_TOKENS, 256, 0, stream>>>(y, pos, out);
}